// Round 1
// baseline (22588.614 us; speedup 1.0000x reference)
//
#include <hip/hip_runtime.h>

// SineNet: fc1 -> LSTM(sine) -> proj.  B=64 T=1024 I=128 H=512 4H=2048 NS=32
// Round 1: correctness-first baseline.
//  - Fold fc1+input-proj: Wc = W1@W_ih [128x2048], bias2 = b1@W_ih + b_lstm.
//  - Scan: one workgroup per batch element (no inter-WG sync), 512 threads,
//    thread m owns gate columns {m, m+512, m+1024, m+1536} -> i,f,g,o local,
//    c stays in a register. f16 weights + v_dot2_f32_f16, fp32 accum.
//  - Pregates computed in 8-step windows inside the scan (no big P buffer).
//  - Output projection h@Wo+bo fused per step (no h history buffer).

constexpr int Bb = 64;
constexpr int Tt = 1024;
constexpr int Ii = 128;
constexpr int Hh = 512;
constexpr int G4 = 2048;
constexpr int NS = 32;

typedef _Float16 h2 __attribute__((ext_vector_type(2)));
typedef _Float16 h4 __attribute__((ext_vector_type(4)));
typedef _Float16 h8 __attribute__((ext_vector_type(8)));
typedef float    f4 __attribute__((ext_vector_type(4)));

__device__ __forceinline__ float dot8(h8 w, h8 x, float acc) {
  h2 w0 = {w[0], w[1]}, w1 = {w[2], w[3]}, w2 = {w[4], w[5]}, w3 = {w[6], w[7]};
  h2 x0 = {x[0], x[1]}, x1 = {x[2], x[3]}, x2 = {x[4], x[5]}, x3 = {x[6], x[7]};
  acc = __builtin_amdgcn_fdot2(x0, w0, acc, false);
  acc = __builtin_amdgcn_fdot2(x1, w1, acc, false);
  acc = __builtin_amdgcn_fdot2(x2, w2, acc, false);
  acc = __builtin_amdgcn_fdot2(x3, w3, acc, false);
  return acc;
}

__device__ __forceinline__ float sigmoidf_(float x) {
  return 1.f / (1.f + __expf(-x));
}

// ---- x (fp32) -> f16 copy -------------------------------------------------
__global__ void k_cvt(const float* __restrict__ x, _Float16* __restrict__ xh, int n) {
  int i = (blockIdx.x * blockDim.x + threadIdx.x) * 4;
  if (i + 3 < n) {
    f4 v = *(const f4*)(x + i);
    h4 o = {(_Float16)v[0], (_Float16)v[1], (_Float16)v[2], (_Float16)v[3]};
    *(h4*)(xh + i) = o;
  }
}

// ---- Wc = W1@W_ih (fp32 compute) -> f16 tiled layout; bias2 = b1@W_ih + b_lstm
// Wc4 layout (f16): [jb=j>>6][kk=i>>3][jl=j&63][e=i&7]
__global__ void k_wc(const float* __restrict__ W1, const float* __restrict__ Wih,
                     const float* __restrict__ b1, const float* __restrict__ bl,
                     _Float16* __restrict__ Wc4, float* __restrict__ bias2) {
  const int j = blockIdx.x;   // 0..2047
  const int i = threadIdx.x;  // 0..127
  __shared__ float col[Hh];
  __shared__ float part[128];
  for (int k = i; k < Hh; k += 128) col[k] = Wih[k * G4 + j];
  __syncthreads();
  float s = 0.f;
  for (int k = i; k < Hh; k += 128) s += b1[k] * col[k];
  part[i] = s;
  __syncthreads();
  if (i == 0) {
    float t = bl[j];
    for (int k = 0; k < 128; k++) t += part[k];
    bias2[j] = t;
  }
  float acc = 0.f;
  const float* w1r = W1 + i * Hh;
#pragma unroll 4
  for (int k = 0; k < Hh; k++) acc += w1r[k] * col[k];
  Wc4[((j >> 6) * 16 + (i >> 3)) * 512 + (j & 63) * 8 + (i & 7)] = (_Float16)acc;
}

// ---- W_hh (fp32 [512][2048]) -> f16 layout [jb=j>>6][kg=k>>3][jl=j&63][e=k&7]
__global__ void k_whh(const float* __restrict__ W, _Float16* __restrict__ W4) {
  int tid = blockIdx.x * 256 + threadIdx.x;  // < 131072
  int jl = tid & 63, kg = (tid >> 6) & 63, jb = tid >> 12;
  int j = jb * 64 + jl;
  h8 o;
#pragma unroll
  for (int e = 0; e < 8; e++) o[e] = (_Float16)W[(kg * 8 + e) * G4 + j];
  *(h8*)(W4 + ((jb * 64 + kg) * 64 + jl) * 8) = o;
}

// ---- the scan: one block per batch element --------------------------------
__global__ __launch_bounds__(512) void k_scan(
    const _Float16* __restrict__ xh, const _Float16* __restrict__ Wc4,
    const float* __restrict__ bias2, const _Float16* __restrict__ Whh4,
    const float* __restrict__ Wo, const float* __restrict__ bo,
    float* __restrict__ out) {
  const int b = blockIdx.x;
  const int tid = threadIdx.x;  // 0..511, owns hidden unit m = tid

  __shared__ __align__(16) h2 hh[Hh / 2];        // h state, f16
  __shared__ __align__(16) h2 xw[8][Ii / 2];     // x window, f16
  __shared__ __align__(16) h2 wot[NS][260];      // Wo^T as pairs (padded rows)
  __shared__ float op[NS][17];                   // out-proj partials

  // init
  if (tid < Hh / 2) { h2 z = {(_Float16)0.f, (_Float16)0.f}; hh[tid] = z; }
  for (int idx = tid; idx < NS * (Hh / 2); idx += 512) {
    int n = idx >> 8, mp = idx & 255;
    h2 v = {(_Float16)Wo[(2 * mp) * NS + n], (_Float16)Wo[(2 * mp + 1) * NS + n]};
    wot[n][mp] = v;
  }
  float creg = 0.f;                         // cell state for unit m
  const float boreg = (tid < NS) ? bo[tid] : 0.f;

  const int m = tid;
  const int ci = m, cf = m + 512, cg = m + 1024, co = m + 1536;
  const h8* wpI = (const h8*)Whh4 + ((ci >> 6) * 4096 + (ci & 63));
  const h8* wpF = (const h8*)Whh4 + ((cf >> 6) * 4096 + (cf & 63));
  const h8* wpG = (const h8*)Whh4 + ((cg >> 6) * 4096 + (cg & 63));
  const h8* wpO = (const h8*)Whh4 + ((co >> 6) * 4096 + (co & 63));
  const h8* wcI = (const h8*)Wc4 + ((ci >> 6) * 1024 + (ci & 63));
  const h8* wcF = (const h8*)Wc4 + ((cf >> 6) * 1024 + (cf & 63));
  const h8* wcG = (const h8*)Wc4 + ((cg >> 6) * 1024 + (cg & 63));
  const h8* wcO = (const h8*)Wc4 + ((co >> 6) * 1024 + (co & 63));
  const float bI = bias2[ci], bF = bias2[cf], bG = bias2[cg], bO = bias2[co];

#pragma unroll 1
  for (int tw = 0; tw < Tt / 8; ++tw) {
    const int t0 = tw * 8;
    // stage 8 timesteps of x (this thread's batch row) into LDS
    {
      int ttl = tid >> 6, i2 = tid & 63;
      xw[ttl][i2] = ((const h2*)xh)[(b * Tt + t0 + ttl) * (Ii / 2) + i2];
    }
    __syncthreads();
    // pregates for the window: pX[tt] = bias2 + x_t @ Wc   (K=128)
    float pI[8], pF[8], pG[8], pO[8];
#pragma unroll
    for (int q = 0; q < 8; q++) { pI[q] = bI; pF[q] = bF; pG[q] = bG; pO[q] = bO; }
#pragma unroll 4
    for (int kk = 0; kk < 16; ++kk) {
      h8 wI = wcI[kk * 64];
      h8 wF = wcF[kk * 64];
      h8 wG = wcG[kk * 64];
      h8 wO = wcO[kk * 64];
#pragma unroll
      for (int q = 0; q < 8; q++) {
        h8 xv = *(const h8*)&xw[q][kk * 4];
        pI[q] = dot8(wI, xv, pI[q]);
        pF[q] = dot8(wF, xv, pF[q]);
        pG[q] = dot8(wG, xv, pG[q]);
        pO[q] = dot8(wO, xv, pO[q]);
      }
    }
#pragma unroll
    for (int tt = 0; tt < 8; ++tt) {
      const int t = t0 + tt;
      // gates = pregate + h @ W_hh   (K=512, f16 weights, fp32 accum)
      float aI = pI[tt], aF = pF[tt], aG = pG[tt], aO = pO[tt];
#pragma unroll 4
      for (int kg = 0; kg < 64; ++kg) {
        h8 hv = *(const h8*)&hh[kg * 4];
        aI = dot8(wpI[kg * 64], hv, aI);
        aF = dot8(wpF[kg * 64], hv, aF);
        aG = dot8(wpG[kg * 64], hv, aG);
        aO = dot8(wpO[kg * 64], hv, aO);
      }
      float iv = sigmoidf_(aI);
      float fv = sigmoidf_(aF);
      float gv = __sinf(aG);
      float ov = sigmoidf_(aO);
      float cn = fv * creg + iv * gv;
      creg = cn;
      float hn = ov * __sinf(cn);
      __syncthreads();                    // everyone done READING hh
      ((_Float16*)hh)[m] = (_Float16)hn;  // publish new h
      __syncthreads();                    // hh ready
      // fused output projection: out[b][t][:] = h @ Wo + bo
      {
        const int n = tid & 31, p = tid >> 5;  // p in [0,16)
        const h2* hp = &hh[p * 16];
        const h2* wq = &wot[n][p * 16];
        float acc = 0.f;
#pragma unroll
        for (int q = 0; q < 16; q++)
          acc = __builtin_amdgcn_fdot2(hp[q], wq[q], acc, false);
        op[n][p] = acc;
      }
      __syncthreads();                    // partials ready
      if (tid < NS) {
        float s2 = boreg;
#pragma unroll
        for (int p = 0; p < 16; p++) s2 += op[tid][p];
        out[(b * Tt + t) * NS + tid] = s2;
      }
    }
  }
}

extern "C" void kernel_launch(void* const* d_in, const int* in_sizes, int n_in,
                              void* d_out, int out_size, void* d_ws, size_t ws_size,
                              hipStream_t stream) {
  const float* x   = (const float*)d_in[0];
  const float* W1  = (const float*)d_in[1];
  const float* b1  = (const float*)d_in[2];
  const float* Wih = (const float*)d_in[3];
  const float* Whh = (const float*)d_in[4];
  const float* bl  = (const float*)d_in[5];
  const float* Wo  = (const float*)d_in[6];
  const float* bo  = (const float*)d_in[7];
  float* out = (float*)d_out;

  char* ws = (char*)d_ws;
  _Float16* xh    = (_Float16*)ws;                                        // 16 MB
  _Float16* Wc4   = (_Float16*)(ws + (16u << 20));                        // 512 KB
  float*    bias2 = (float*)(ws + (16u << 20) + (512u << 10));            // 8 KB
  _Float16* Whh4  = (_Float16*)(ws + (16u << 20) + (512u << 10) + (8u << 10));  // 2 MB

  k_cvt<<<8192, 256, 0, stream>>>(x, xh, Bb * Tt * Ii);
  k_wc<<<G4, 128, 0, stream>>>(W1, Wih, b1, bl, Wc4, bias2);
  k_whh<<<512, 256, 0, stream>>>(Whh, Whh4);
  k_scan<<<Bb, 512, 0, stream>>>(xh, Wc4, bias2, Whh4, Wo, bo, out);
}

// Round 3
// 9929.601 us; speedup vs baseline: 2.2749x; 2.2749x over previous
//
#include <hip/hip_runtime.h>

// SineNet: fc1 -> LSTM(sine) -> proj.  B=64 T=1024 I=128 H=512 4H=2048 NS=32
// Round 3: weight-stationary persistent scan (R2 design, fence spelling fixed).
//  - 64 persistent WGs (1/CU), WG j owns hidden units m in [8j, 8j+8).
//  - W_hh (f16) lives in VGPRs as MFMA B-fragments: wave w of WG j owns
//    16-col block cb=2j+(w&1): cb even = {i|f} cols, odd = {g|o} cols.
//  - Per step: gates = h@W_hh via mfma_f32_16x16x32_f16 (h staged in LDS,
//    XOR-swizzled), + pregate (x@Wc, computed per 2-step window via MFMA),
//    elementwise in fp32, h broadcast through LLC with per-step flag barrier.
//  - Out projection h@Wo+bo fused per step from the staged h.
// Barrier protocol: per-(t,wg) flag slot (no ABA), release store after
// __syncthreads (vmcnt drained) -> wbl2; readers poll relaxed then one
// acquire fence (buffer_inv) before re-reading hbuf. Double-buffered hbuf:
// a WG can only write buf[t&1] at step t+2 after passing flags[t+1], which
// requires every WG's step-t staging read of buf[t&1] to have finished.

constexpr int Bb = 64;
constexpr int Tt = 1024;
constexpr int Ii = 128;
constexpr int Hh = 512;
constexpr int G4 = 2048;
constexpr int NS = 32;
constexpr int NWG = 64;

typedef _Float16 h2 __attribute__((ext_vector_type(2)));
typedef _Float16 h8 __attribute__((ext_vector_type(8)));
typedef float    f4 __attribute__((ext_vector_type(4)));

__device__ __forceinline__ float dot8(h8 w, h8 x, float acc) {
  h2 w0 = {w[0], w[1]}, w1 = {w[2], w[3]}, w2 = {w[4], w[5]}, w3 = {w[6], w[7]};
  h2 x0 = {x[0], x[1]}, x1 = {x[2], x[3]}, x2 = {x[4], x[5]}, x3 = {x[6], x[7]};
  acc = __builtin_amdgcn_fdot2(x0, w0, acc, false);
  acc = __builtin_amdgcn_fdot2(x1, w1, acc, false);
  acc = __builtin_amdgcn_fdot2(x2, w2, acc, false);
  acc = __builtin_amdgcn_fdot2(x3, w3, acc, false);
  return acc;
}

__device__ __forceinline__ float sigf(float x) { return 1.f / (1.f + __expf(-x)); }

// ---- Wc = W1@W_ih (fp32) -> f16 B-fragment layout; bias2 = b1@W_ih + b_lstm
// Fragment layout: Wc4[((cb*4 + ks)*64 + lane)*8 + e] where element is
// Wc[k = ks*32 + (lane>>4)*8 + e][global col of (cb, c=lane&15)].
__global__ void k_wc(const float* __restrict__ W1, const float* __restrict__ Wih,
                     const float* __restrict__ b1, const float* __restrict__ bl,
                     _Float16* __restrict__ Wc4, float* __restrict__ bias2) {
  const int j = blockIdx.x;   // global gate col 0..2047
  const int i = threadIdx.x;  // k index 0..127
  __shared__ float col[Hh];
  __shared__ float part[128];
  for (int k = i; k < Hh; k += 128) col[k] = Wih[k * G4 + j];
  __syncthreads();
  float s = 0.f;
  for (int k = i; k < Hh; k += 128) s += b1[k] * col[k];
  part[i] = s;
  __syncthreads();
  if (i == 0) {
    float t = bl[j];
    for (int k = 0; k < 128; k++) t += part[k];
    bias2[j] = t;
  }
  float acc = 0.f;
  const float* w1r = W1 + i * Hh;
#pragma unroll 4
  for (int k = 0; k < Hh; k++) acc += w1r[k] * col[k];
  // map global col j -> (cb, c): cb = 2*jj + (gate>>1), c = (gate&1)*8 + (j&7)
  const int gate = j >> 9, jj = (j >> 3) & 63, c8 = j & 7;
  const int cb = 2 * jj + (gate >> 1);
  const int c  = (gate & 1) * 8 + c8;
  const int ks = i >> 5, lane = ((i >> 3) & 3) * 16 + c, e = i & 7;
  Wc4[((cb * 4 + ks) * 64 + lane) * 8 + e] = (_Float16)acc;
}

// ---- W_hh (fp32 [512][2048]) -> f16 B-fragment layout
// Whh4[((cb*16 + ks)*64 + lane)*8 + e] = Whh[ks*32 + (lane>>4)*8 + e][col(cb, lane&15)]
__global__ void k_whh(const float* __restrict__ W, _Float16* __restrict__ W4) {
  const int id = blockIdx.x * 256 + threadIdx.x;  // < 131072
  const int lane = id & 63, ks = (id >> 6) & 15, cb = id >> 10;
  const int c = lane & 15, q = lane >> 4;
  const int jj = cb >> 1, gp = cb & 1;
  const int gate = gp * 2 + (c >> 3);
  const int col = gate * 512 + jj * 8 + (c & 7);
  h8 o;
#pragma unroll
  for (int e = 0; e < 8; ++e) o[e] = (_Float16)W[(ks * 32 + q * 8 + e) * G4 + col];
  *(h8*)(W4 + ((cb * 16 + ks) * 64 + lane) * 8) = o;
}

// ---- persistent scan ------------------------------------------------------
__global__ __launch_bounds__(512, 1) void k_scan(
    const float* __restrict__ x, const _Float16* __restrict__ Wc4,
    const float* __restrict__ bias2, const _Float16* __restrict__ Whh4,
    const float* __restrict__ Wo, const float* __restrict__ bo,
    float* __restrict__ out, _Float16* __restrict__ hbuf, int* __restrict__ flags) {
  const int j = blockIdx.x;       // WG id = m-group = batch for out-proj
  const int tid = threadIdx.x;
  const int lane = tid & 63, wv = tid >> 6;
  const int mt = wv >> 1, nt = wv & 1;   // M-tile (batches), N-tile (col half)
  const int cb = 2 * j + nt;
  const int l15 = lane & 15, l4 = lane >> 4;

  __shared__ __align__(16) char hls[65536];   // h [64][512] f16, XOR-swizzled
  __shared__ __align__(16) char xws[32768];   // x window [128][128] f16, swizzled
  __shared__ __align__(16) char wots[32768];  // Wo^T [32][512] f16, swizzled
  __shared__ float pre_s[2][64][33];          // pregates (padded)
  __shared__ float gat_s[64][33];             // h@Whh result (padded)
  __shared__ float op_s[32][17];              // out-proj partials

  // B fragments: register-resident weights
  h8 bW[16], bC[4];
#pragma unroll
  for (int ks = 0; ks < 16; ++ks)
    bW[ks] = *(const h8*)(Whh4 + ((cb * 16 + ks) * 64 + lane) * 8);
#pragma unroll
  for (int ks = 0; ks < 4; ++ks)
    bC[ks] = *(const h8*)(Wc4 + ((cb * 4 + ks) * 64 + lane) * 8);

  const int b8 = tid >> 3, ml = tid & 7;  // elementwise role: (batch, m-local)
  const float bI = bias2[j * 8 + ml],        bF = bias2[512 + j * 8 + ml],
              bG = bias2[1024 + j * 8 + ml], bO = bias2[1536 + j * 8 + ml];
  const int nn = tid & 31, pp = tid >> 5;  // out-proj role
  const float bor = (tid < NS) ? bo[tid] : 0.f;

  // init: zero h state, stage Wo^T (f16, swizzled)
#pragma unroll
  for (int q = 0; q < 8; ++q) {
    int n = q * 512 + tid;
    int row = n >> 6, cc = n & 63;
    h8 z = {};
    *(h8*)(hls + row * 1024 + ((cc * 16) ^ ((row & 7) << 4))) = z;
  }
  for (int it = tid; it < Hh * NS; it += 512) {
    int k = it >> 5, n = it & 31;
    *(_Float16*)(wots + n * 1024 + ((2 * k) ^ ((n & 7) << 4))) = (_Float16)Wo[k * NS + n];
  }
  float c_ = 0.f;
  __syncthreads();

  _Float16* const hb0 = hbuf;
  _Float16* const hb1 = hbuf + Bb * Hh;

  for (int t = 0; t < Tt; ++t) {
    const int tph = t & 1;
    _Float16* const hbt = tph ? hb1 : hb0;
    if (tph == 0) {
      // stage x window: rows r = tt*64+b, cols i (f32 global -> f16 LDS)
#pragma unroll
      for (int q = 0; q < 4; ++q) {
        int n = q * 512 + tid;
        int row = n >> 4, cc = n & 15;
        int b2 = row & 63, tt2 = row >> 6;
        const float* src = x + ((size_t)b2 * Tt + (t + tt2)) * Ii + cc * 8;
        f4 s0 = *(const f4*)src, s1 = *(const f4*)(src + 4);
        h8 v = {(_Float16)s0[0], (_Float16)s0[1], (_Float16)s0[2], (_Float16)s0[3],
                (_Float16)s1[0], (_Float16)s1[1], (_Float16)s1[2], (_Float16)s1[3]};
        *(h8*)(xws + row * 256 + ((cc * 16) ^ ((row & 7) << 4))) = v;
      }
      __syncthreads();
      // pregate MFMA: [128 rows][32 cols] += xw @ Wc   (K=128)
#pragma unroll
      for (int r2 = 0; r2 < 2; ++r2) {
        const int rt = (wv >> 1) + r2 * 4;
        f4 pa = {0.f, 0.f, 0.f, 0.f};
#pragma unroll
        for (int ks = 0; ks < 4; ++ks) {
          const int row = rt * 16 + l15;
          h8 a = *(const h8*)(xws + row * 256 + ((ks * 64 + l4 * 16) ^ ((row & 7) << 4)));
          pa = __builtin_amdgcn_mfma_f32_16x16x32_f16(a, bC[ks], pa, 0, 0, 0);
        }
#pragma unroll
        for (int e = 0; e < 4; ++e)
          pre_s[rt >> 2][(rt & 3) * 16 + l4 * 4 + e][nt * 16 + l15] = pa[e];
      }
    }
    // gate GEMM: gates[64][32] = h_prev @ W_hh   (K=512)
    {
      f4 g0 = {0.f, 0.f, 0.f, 0.f}, g1 = {0.f, 0.f, 0.f, 0.f};
#pragma unroll
      for (int ks = 0; ks < 16; ++ks) {
        const int row = mt * 16 + l15;
        h8 a = *(const h8*)(hls + row * 1024 + ((ks * 64 + l4 * 16) ^ ((row & 7) << 4)));
        if (ks & 1) g1 = __builtin_amdgcn_mfma_f32_16x16x32_f16(a, bW[ks], g1, 0, 0, 0);
        else        g0 = __builtin_amdgcn_mfma_f32_16x16x32_f16(a, bW[ks], g0, 0, 0, 0);
      }
#pragma unroll
      for (int e = 0; e < 4; ++e)
        gat_s[mt * 16 + l4 * 4 + e][nt * 16 + l15] = g0[e] + g1[e];
    }
    __syncthreads();
    // elementwise LSTM cell + publish h slice
    {
      float aI = gat_s[b8][ml]      + pre_s[tph][b8][ml]      + bI;
      float aF = gat_s[b8][8 + ml]  + pre_s[tph][b8][8 + ml]  + bF;
      float aG = gat_s[b8][16 + ml] + pre_s[tph][b8][16 + ml] + bG;
      float aO = gat_s[b8][24 + ml] + pre_s[tph][b8][24 + ml] + bO;
      float iv = sigf(aI), fv = sigf(aF), gv = __sinf(aG), ov = sigf(aO);
      c_ = fv * c_ + iv * gv;
      float hn = ov * __sinf(c_);
      hbt[b8 * Hh + j * 8 + ml] = (_Float16)hn;
    }
    __syncthreads();  // all threads' h stores issued before flag path
    if (tid == 0)
      __hip_atomic_store(&flags[t * NWG + j], 1, __ATOMIC_RELEASE, __HIP_MEMORY_SCOPE_AGENT);
    if (tid < NWG) {
      while (__hip_atomic_load(&flags[t * NWG + tid], __ATOMIC_RELAXED,
                               __HIP_MEMORY_SCOPE_AGENT) == 0)
        __builtin_amdgcn_s_sleep(2);
    }
    __syncthreads();
    __builtin_amdgcn_fence(__ATOMIC_ACQUIRE, "agent");
    // re-stage full h into LDS (swizzled)
#pragma unroll
    for (int q = 0; q < 8; ++q) {
      int n = q * 512 + tid;
      int row = n >> 6, cc = n & 63;
      *(h8*)(hls + row * 1024 + ((cc * 16) ^ ((row & 7) << 4))) = *(const h8*)(hbt + n * 8);
    }
    __syncthreads();
    // fused out projection for batch j: out[j][t][:] = h_t[j] @ Wo + bo
    {
      float acc = 0.f;
#pragma unroll
      for (int q = 0; q < 4; ++q) {
        h8 wv_ = *(const h8*)(wots + nn * 1024 + ((pp * 64 + q * 16) ^ ((nn & 7) << 4)));
        h8 hv  = *(const h8*)(hls + j * 1024 + ((pp * 64 + q * 16) ^ ((j & 7) << 4)));
        acc = dot8(wv_, hv, acc);
      }
      op_s[nn][pp] = acc;
    }
    __syncthreads();
    if (tid < NS) {
      float s = bor;
#pragma unroll
      for (int p = 0; p < 16; ++p) s += op_s[tid][p];
      out[((size_t)j * Tt + t) * NS + tid] = s;
    }
  }
}

extern "C" void kernel_launch(void* const* d_in, const int* in_sizes, int n_in,
                              void* d_out, int out_size, void* d_ws, size_t ws_size,
                              hipStream_t stream) {
  const float* x   = (const float*)d_in[0];
  const float* W1  = (const float*)d_in[1];
  const float* b1  = (const float*)d_in[2];
  const float* Wih = (const float*)d_in[3];
  const float* Whh = (const float*)d_in[4];
  const float* bl  = (const float*)d_in[5];
  const float* Wo  = (const float*)d_in[6];
  const float* bo  = (const float*)d_in[7];
  float* out = (float*)d_out;

  char* ws = (char*)d_ws;
  _Float16* Wc4   = (_Float16*)(ws);                 // 512 KB
  float*    bias2 = (float*)(ws + 524288);           // 8 KB
  _Float16* Whh4  = (_Float16*)(ws + 532480);        // 2 MB
  _Float16* hbuf  = (_Float16*)(ws + 2629632);       // 128 KB (double buffer)
  int*      flags = (int*)(ws + 2760704);            // 256 KB (per-(t,wg) slots)

  (void)hipMemsetAsync(flags, 0, Tt * NWG * sizeof(int), stream);
  k_wc<<<G4, 128, 0, stream>>>(W1, Wih, b1, bl, Wc4, bias2);
  k_whh<<<512, 256, 0, stream>>>(Whh, Whh4);
  k_scan<<<NWG, 512, 0, stream>>>(x, Wc4, bias2, Whh4, Wo, bo, out, hbuf, flags);
}

// Round 4
// 3850.689 us; speedup vs baseline: 5.8661x; 2.5787x over previous
//
#include <hip/hip_runtime.h>

// SineNet: fc1 -> LSTM(sine) -> proj.  B=64 T=1024 I=128 H=512 4H=2048 NS=32
// Round 4: fence-free coherent exchange + latency-shadowed schedule.
//  - 64 persistent WGs, WG j owns 8 hidden units; W_hh/Wc as register B-frags.
//  - Cross-WG h exchange via sc0+sc1 (LLC-coherent, bypass L1/L2) dwordx4
//    loads/stores -> NO buffer_wbl2 / buffer_inv cache-maintenance per step.
//  - Release order: publish stores -> s_waitcnt vmcnt(0) -> relaxed flag store.
//    Acquire: poll relaxed flag -> barrier -> sc0sc1 loads (never stale).
//  - Shadow work between flag-publish and poll: pregate MFMA (odd t),
//    x window staging (even t), out-projection partials (every t).
//  - 4 barriers/step. hbuf b-major: coalesced restage + conflict-free LDS.

constexpr int Bb = 64;
constexpr int Tt = 1024;
constexpr int Ii = 128;
constexpr int Hh = 512;
constexpr int G4 = 2048;
constexpr int NS = 32;
constexpr int NWG = 64;

typedef _Float16 h2 __attribute__((ext_vector_type(2)));
typedef _Float16 h8 __attribute__((ext_vector_type(8)));
typedef float    f4 __attribute__((ext_vector_type(4)));
typedef unsigned int u32;
typedef u32 u32x4 __attribute__((ext_vector_type(4)));

__device__ __forceinline__ float dot8(h8 w, h8 x, float acc) {
  h2 w0 = {w[0], w[1]}, w1 = {w[2], w[3]}, w2 = {w[4], w[5]}, w3 = {w[6], w[7]};
  h2 x0 = {x[0], x[1]}, x1 = {x[2], x[3]}, x2 = {x[4], x[5]}, x3 = {x[6], x[7]};
  acc = __builtin_amdgcn_fdot2(x0, w0, acc, false);
  acc = __builtin_amdgcn_fdot2(x1, w1, acc, false);
  acc = __builtin_amdgcn_fdot2(x2, w2, acc, false);
  acc = __builtin_amdgcn_fdot2(x3, w3, acc, false);
  return acc;
}

__device__ __forceinline__ float sigf(float x) { return 1.f / (1.f + __expf(-x)); }

// ---- Wc = W1@W_ih (fp32) -> f16 B-fragment layout; bias2 = b1@W_ih + b_lstm
__global__ void k_wc(const float* __restrict__ W1, const float* __restrict__ Wih,
                     const float* __restrict__ b1, const float* __restrict__ bl,
                     _Float16* __restrict__ Wc4, float* __restrict__ bias2) {
  const int j = blockIdx.x;   // global gate col 0..2047
  const int i = threadIdx.x;  // k index 0..127
  __shared__ float col[Hh];
  __shared__ float part[128];
  for (int k = i; k < Hh; k += 128) col[k] = Wih[k * G4 + j];
  __syncthreads();
  float s = 0.f;
  for (int k = i; k < Hh; k += 128) s += b1[k] * col[k];
  part[i] = s;
  __syncthreads();
  if (i == 0) {
    float t = bl[j];
    for (int k = 0; k < 128; k++) t += part[k];
    bias2[j] = t;
  }
  float acc = 0.f;
  const float* w1r = W1 + i * Hh;
#pragma unroll 4
  for (int k = 0; k < Hh; k++) acc += w1r[k] * col[k];
  const int gate = j >> 9, jj = (j >> 3) & 63, c8 = j & 7;
  const int cb = 2 * jj + (gate >> 1);
  const int c  = (gate & 1) * 8 + c8;
  const int ks = i >> 5, lane = ((i >> 3) & 3) * 16 + c, e = i & 7;
  Wc4[((cb * 4 + ks) * 64 + lane) * 8 + e] = (_Float16)acc;
}

// ---- W_hh (fp32 [512][2048]) -> f16 B-fragment layout
__global__ void k_whh(const float* __restrict__ W, _Float16* __restrict__ W4) {
  const int id = blockIdx.x * 256 + threadIdx.x;  // < 131072
  const int lane = id & 63, ks = (id >> 6) & 15, cb = id >> 10;
  const int c = lane & 15, q = lane >> 4;
  const int jj = cb >> 1, gp = cb & 1;
  const int gate = gp * 2 + (c >> 3);
  const int col = gate * 512 + jj * 8 + (c & 7);
  h8 o;
#pragma unroll
  for (int e = 0; e < 8; ++e) o[e] = (_Float16)W[(ks * 32 + q * 8 + e) * G4 + col];
  *(h8*)(W4 + ((cb * 16 + ks) * 64 + lane) * 8) = o;
}

// ---- persistent scan ------------------------------------------------------
__global__ __launch_bounds__(512, 1) void k_scan(
    const float* __restrict__ x, const _Float16* __restrict__ Wc4,
    const float* __restrict__ bias2, const _Float16* __restrict__ Whh4,
    const float* __restrict__ Wo, const float* __restrict__ bo,
    float* __restrict__ out, u32* __restrict__ hbuf, int* __restrict__ flags) {
  const int j = blockIdx.x;
  const int tid = threadIdx.x;
  const int lane = tid & 63, wv = tid >> 6;
  const int mt = wv >> 1, nt = wv & 1;
  const int cb = 2 * j + nt;
  const int l15 = lane & 15, l4 = lane >> 4;

  __shared__ __align__(16) char hls[65536];   // h [64 rows][512] f16, swizzled
  __shared__ __align__(16) char xws[32768];   // x window [128][128] f16, swizzled
  __shared__ __align__(16) char wots[32768];  // Wo^T [32][512] f16, swizzled
  __shared__ float pre_s[2][64][33];
  __shared__ float gat_s[64][33];
  __shared__ __align__(16) u32 hxs[256];      // packed new-h pairs [64b][4]
  __shared__ float op_s[32][17];

  h8 bW[16], bC[4];
#pragma unroll
  for (int ks = 0; ks < 16; ++ks)
    bW[ks] = *(const h8*)(Whh4 + ((cb * 16 + ks) * 64 + lane) * 8);
#pragma unroll
  for (int ks = 0; ks < 4; ++ks)
    bC[ks] = *(const h8*)(Wc4 + ((cb * 4 + ks) * 64 + lane) * 8);

  const int b8 = tid >> 3, ml = tid & 7;
  const float bI = bias2[j * 8 + ml],        bF = bias2[512 + j * 8 + ml],
              bG = bias2[1024 + j * 8 + ml], bO = bias2[1536 + j * 8 + ml];
  const int nn = tid & 31, pp = tid >> 5;
  const float bor = (tid < NS) ? bo[tid] : 0.f;

  // init: zero h, stage Wo^T
#pragma unroll
  for (int q = 0; q < 8; ++q) {
    int n = q * 512 + tid;
    int row = n >> 6, cc = n & 63;
    h8 z = {};
    *(h8*)(hls + row * 1024 + ((cc * 16) ^ ((row & 7) << 4))) = z;
  }
  for (int it = tid; it < Hh * NS; it += 512) {
    int k = it >> 5, n = it & 31;
    *(_Float16*)(wots + n * 1024 + ((2 * k) ^ ((n & 7) << 4))) = (_Float16)Wo[k * NS + n];
  }
  float c_ = 0.f;

  auto stage_x = [&](int t0) {  // stage steps {t0, t0+1}: rows tt2*64+b2
#pragma unroll
    for (int q = 0; q < 4; ++q) {
      int n = q * 512 + tid;
      int row = n >> 4, cc = n & 15;
      int b2 = row & 63, tt2 = row >> 6;
      const float* src = x + ((size_t)b2 * Tt + (t0 + tt2)) * Ii + cc * 8;
      f4 s0 = *(const f4*)src, s1 = *(const f4*)(src + 4);
      h8 v = {(_Float16)s0[0], (_Float16)s0[1], (_Float16)s0[2], (_Float16)s0[3],
              (_Float16)s1[0], (_Float16)s1[1], (_Float16)s1[2], (_Float16)s1[3]};
      *(h8*)(xws + row * 256 + ((cc * 16) ^ ((row & 7) << 4))) = v;
    }
  };
  auto do_pregate = [&]() {  // pre_s[tt2] for the 2 staged steps
#pragma unroll
    for (int r2 = 0; r2 < 2; ++r2) {
      const int rt = (wv >> 1) + r2 * 4;
      f4 pa = {0.f, 0.f, 0.f, 0.f};
#pragma unroll
      for (int ks = 0; ks < 4; ++ks) {
        const int row = rt * 16 + l15;
        h8 a = *(const h8*)(xws + row * 256 + ((ks * 64 + l4 * 16) ^ ((row & 7) << 4)));
        pa = __builtin_amdgcn_mfma_f32_16x16x32_f16(a, bC[ks], pa, 0, 0, 0);
      }
#pragma unroll
      for (int e = 0; e < 4; ++e)
        pre_s[rt >> 2][(rt & 3) * 16 + l4 * 4 + e][nt * 16 + l15] = pa[e];
    }
  };
  auto outproj_part = [&]() {  // partials of h[row j] @ Wo from hls
    float acc = 0.f;
#pragma unroll
    for (int q = 0; q < 4; ++q) {
      h8 wv_ = *(const h8*)(wots + nn * 1024 + ((pp * 64 + q * 16) ^ ((nn & 7) << 4)));
      h8 hv  = *(const h8*)(hls + j * 1024 + ((pp * 64 + q * 16) ^ ((j & 7) << 4)));
      acc = dot8(wv_, hv, acc);
    }
    op_s[nn][pp] = acc;
  };

  stage_x(0);
  __syncthreads();   // xws + hls-zero + wots ready
  do_pregate();      // pre_s slots {0,1} for steps 0,1

  for (int t = 0; t < Tt; ++t) {
    const int tph = t & 1;
    u32* const hbt = hbuf + tph * (Bb * 256);
    // gate GEMM: gat_s[64][32] = h_prev @ W_hh (K=512)
    {
      f4 g0 = {0.f, 0.f, 0.f, 0.f}, g1 = {0.f, 0.f, 0.f, 0.f};
#pragma unroll
      for (int ks = 0; ks < 16; ++ks) {
        const int row = mt * 16 + l15;
        h8 a = *(const h8*)(hls + row * 1024 + ((ks * 64 + l4 * 16) ^ ((row & 7) << 4)));
        if (ks & 1) g1 = __builtin_amdgcn_mfma_f32_16x16x32_f16(a, bW[ks], g1, 0, 0, 0);
        else        g0 = __builtin_amdgcn_mfma_f32_16x16x32_f16(a, bW[ks], g0, 0, 0, 0);
      }
#pragma unroll
      for (int e = 0; e < 4; ++e)
        gat_s[mt * 16 + l4 * 4 + e][nt * 16 + l15] = g0[e] + g1[e];
    }
    __syncthreads();  // B1: gat_s ready
    // cell update -> hxs (packed f16 pairs)
    {
      float aI = gat_s[b8][ml]      + pre_s[tph][b8][ml]      + bI;
      float aF = gat_s[b8][8 + ml]  + pre_s[tph][b8][8 + ml]  + bF;
      float aG = gat_s[b8][16 + ml] + pre_s[tph][b8][16 + ml] + bG;
      float aO = gat_s[b8][24 + ml] + pre_s[tph][b8][24 + ml] + bO;
      float iv = sigf(aI), fv = sigf(aF), gv = __sinf(aG), ov = sigf(aO);
      c_ = fv * c_ + iv * gv;
      float hn = ov * __sinf(c_);
      ((_Float16*)hxs)[tid] = (_Float16)hn;  // [b8][ml]
    }
    __syncthreads();  // B2: hxs ready
    // publish (wave 0): 16B coherent store per batch row
    if (tid < 64) {
      u32x4 v = *(const u32x4*)((const char*)hxs + tid * 16);
      const u32* dst = hbt + tid * 256 + j * 4;
      asm volatile("global_store_dwordx4 %0, %1, off sc0 sc1" :: "v"(dst), "v"(v) : "memory");
    }
    asm volatile("s_waitcnt vmcnt(0)" ::: "memory");
    if (tid == 0)
      __hip_atomic_store(&flags[t * NWG + j], 1, __ATOMIC_RELAXED, __HIP_MEMORY_SCOPE_AGENT);
    // ---- shadow work (no remote deps) ----
    if (tph == 0) { if (t <= 1020) stage_x(t + 2); }
    else if (t <= 1021) do_pregate();
    if (t > 0) outproj_part();   // out[t-1] partials from hls (= h_{t-1})
    // poll
    if (tid < NWG) {
      while (!__hip_atomic_load(&flags[t * NWG + tid], __ATOMIC_RELAXED,
                                __HIP_MEMORY_SCOPE_AGENT))
        __builtin_amdgcn_s_sleep(1);
    }
    __syncthreads();  // B3: all WGs published h_t; shadow writes visible
    if (t > 0 && tid < NS) {
      float s = bor;
#pragma unroll
      for (int p = 0; p < 16; ++p) s += op_s[tid][p];
      out[((size_t)j * Tt + (t - 1)) * NS + tid] = s;
    }
    // restage h_t: coherent dwordx4 loads, swizzled b128 LDS writes
    {
      u32x4 r[8];
#pragma unroll
      for (int q = 0; q < 8; ++q)
        asm volatile("global_load_dwordx4 %0, %1, off sc0 sc1"
                     : "=v"(r[q]) : "v"(hbt + q * 2048 + 4 * tid));
      asm volatile("s_waitcnt vmcnt(0)" ::: "memory");
      __builtin_amdgcn_sched_barrier(0);
#pragma unroll
      for (int q = 0; q < 8; ++q) {
        const int b = q * 8 + (tid >> 6);
        *(u32x4*)(hls + b * 1024 + ((16 * (tid & 63)) ^ ((b & 7) << 4))) = r[q];
      }
    }
    __syncthreads();  // B4: hls = h_t
  }
  // epilogue: out[1023]
  outproj_part();
  __syncthreads();
  if (tid < NS) {
    float s = bor;
#pragma unroll
    for (int p = 0; p < 16; ++p) s += op_s[tid][p];
    out[((size_t)j * Tt + 1023) * NS + tid] = s;
  }
}

extern "C" void kernel_launch(void* const* d_in, const int* in_sizes, int n_in,
                              void* d_out, int out_size, void* d_ws, size_t ws_size,
                              hipStream_t stream) {
  const float* x   = (const float*)d_in[0];
  const float* W1  = (const float*)d_in[1];
  const float* b1  = (const float*)d_in[2];
  const float* Wih = (const float*)d_in[3];
  const float* Whh = (const float*)d_in[4];
  const float* bl  = (const float*)d_in[5];
  const float* Wo  = (const float*)d_in[6];
  const float* bo  = (const float*)d_in[7];
  float* out = (float*)d_out;

  char* ws = (char*)d_ws;
  _Float16* Wc4   = (_Float16*)(ws);                 // 512 KB
  float*    bias2 = (float*)(ws + 524288);           // 8 KB
  _Float16* Whh4  = (_Float16*)(ws + 532480);        // 2 MB
  u32*      hbuf  = (u32*)(ws + 2629632);            // 128 KB (double buffer)
  int*      flags = (int*)(ws + 2760704);            // 256 KB (per-(t,wg) slots)

  (void)hipMemsetAsync(flags, 0, Tt * NWG * sizeof(int), stream);
  k_wc<<<G4, 128, 0, stream>>>(W1, Wih, b1, bl, Wc4, bias2);
  k_whh<<<512, 256, 0, stream>>>(Whh, Whh4);
  k_scan<<<NWG, 512, 0, stream>>>(x, Wc4, bias2, Whh4, Wo, bo, out, hbuf, flags);
}